// Round 10
// baseline (1498.402 us; speedup 1.0000x reference)
//
#include <hip/hip_runtime.h>
#include <hip/hip_bf16.h>

#define FIN 512
#define HD 32
#define BN 128       // nodes per fine bucket (bucket = dst >> 7)
#define NB 782       // ceil(100000/128); recomputed at launch, static for LDS sizing
#define NBP 784      // padded
#define AGP 33       // agg row pad (33 floats) -> breaks bank degeneracy
#define CH 8192      // edges per bin chunk
#define NHB 128      // partial-histogram blocks

typedef short s16x8 __attribute__((ext_vector_type(8)));
typedef float f32x4 __attribute__((ext_vector_type(4)));

__device__ inline unsigned short f2b(float f) {  // fp32 -> bf16 bits, RNE
  unsigned u = __float_as_uint(f);
  return (unsigned short)((u + 0x7FFFu + ((u >> 16) & 1u)) >> 16);
}
__device__ inline float b2f(unsigned short b) {
  return __uint_as_float((unsigned)b << 16);
}
__device__ inline float b2f_lo(unsigned u) { return __uint_as_float(u << 16); }
__device__ inline float b2f_hi(unsigned u) { return __uint_as_float(u & 0xFFFF0000u); }

// ---------------- per-block partial histograms over dst>>7 (784 bins) ----------------
__global__ __launch_bounds__(256) void k_bktcnt(const int* __restrict__ dst, int* __restrict__ hist, int E) {
  __shared__ int h[NBP];
  int t = threadIdx.x;
  for (int b = t; b < NBP; b += 256) h[b] = 0;
  __syncthreads();
  for (int i = blockIdx.x * 256 + t; i < E; i += gridDim.x * 256)
    atomicAdd(&h[dst[i] >> 7], 1);
  __syncthreads();
  for (int b = t; b < NBP; b += 256) hist[blockIdx.x * NBP + b] = h[b];
}

// sum partials -> bcnt; exclusive scan -> bbase; init bfill
__global__ __launch_bounds__(1024) void k_bscan(const int* __restrict__ hist, int* __restrict__ bcnt,
                                                int* __restrict__ bbase, int* __restrict__ bfill, int B) {
  __shared__ int s[1024];
  int t = threadIdx.x;
  int v = 0;
  if (t < B)
    for (int b = 0; b < NHB; ++b) v += hist[b * NBP + t];  // independent loads, MLP-friendly
  s[t] = v;
  __syncthreads();
  for (int o = 1; o < 1024; o <<= 1) {
    int a = (t >= o) ? s[t - o] : 0;
    __syncthreads();
    s[t] += a;
    __syncthreads();
  }
  if (t < B) { bcnt[t] = v; bbase[t] = s[t] - v; bfill[t] = s[t] - v; }
}

// ---------------- fine binning: bin[] gets (src | dlow<<20) grouped by dst>>7 ----------------
__global__ __launch_bounds__(512) void k_bin(const int* __restrict__ src, const int* __restrict__ dst,
                                             int* __restrict__ bfill, int* __restrict__ bin, int E) {
  __shared__ int raw[CH];             // 32 KB
  __shared__ unsigned short bkt[CH];  // 16 KB
  __shared__ int cnt[NB];
  __shared__ int gbase[NB];
  int t = threadIdx.x;
  for (int cb = blockIdx.x * CH; cb < E; cb += gridDim.x * CH) {
    int n = E - cb; if (n > CH) n = CH;
    for (int b = t; b < NB; b += 512) cnt[b] = 0;
    __syncthreads();
    for (int j = t; j < n; j += 512) {
      int s = src[cb + j], d = dst[cb + j];
      raw[j] = s | ((d & 127) << 20);
      int b = d >> 7;
      bkt[j] = (unsigned short)b;
      atomicAdd(&cnt[b], 1);
    }
    __syncthreads();
    for (int b = t; b < NB; b += 512) {
      int c = cnt[b];
      gbase[b] = (c > 0) ? atomicAdd(&bfill[b], c) : 0;
      cnt[b] = 0;  // reuse as in-chunk cursor
    }
    __syncthreads();
    for (int j = t; j < n; j += 512) {
      int b = bkt[j];
      int r = atomicAdd(&cnt[b], 1);
      bin[gbase[b] + r] = raw[j];
    }
    __syncthreads();
  }
}

// ---------------- per-bucket degree -> dis (replaces k_csr's exact ordering) ----------------
__global__ __launch_bounds__(256) void k_deg(const int* __restrict__ bin, const int* __restrict__ bbase,
                                             const int* __restrict__ bcnt, float* __restrict__ dis, int N) {
  __shared__ int cnt[BN];
  int t = threadIdx.x;
  int bkt = blockIdx.x, n0 = bkt * BN;
  int nn = N - n0; if (nn > BN) nn = BN;
  if (t < BN) cnt[t] = 0;
  __syncthreads();
  int eb = bbase[bkt], ec = bcnt[bkt];
  for (int j = t; j < ec; j += 256) atomicAdd(&cnt[(unsigned)bin[eb + j] >> 20], 1);
  __syncthreads();
  if (t < nn) dis[n0 + t] = rsqrtf((float)(cnt[t] + 1));
}

// ---------------- mm1 via MFMA: h1b = bf16((x @ W1) * dis[row]) ----------------
#define XPAD 72
#define WPAD 520
__global__ __launch_bounds__(512) void k_mm1(const float* __restrict__ x, const float* __restrict__ W1,
                                             const float* __restrict__ dis, unsigned short* __restrict__ h1b,
                                             int N) {
  __shared__ unsigned short wT[32 * WPAD];
  __shared__ unsigned short xs[128 * XPAD];
  const int t = threadIdx.x;
  const int rbase = blockIdx.x * 128;

  for (int idx = t; idx < FIN * HD; idx += 512) {
    int k = idx >> 5, c = idx & 31;
    wT[c * WPAD + k] = f2b(W1[idx]);
  }

  const int lane = t & 63;
  const int wrow = (t >> 6) * 16;
  const int m16 = lane & 15;
  const int kg = lane >> 4;

  f32x4 acc0 = {0.f, 0.f, 0.f, 0.f};
  f32x4 acc1 = {0.f, 0.f, 0.f, 0.f};

  for (int kc = 0; kc < FIN; kc += 64) {
    __syncthreads();
#pragma unroll
    for (int p = 0; p < 4; ++p) {
      int idx = p * 512 + t;
      int r = idx >> 4, kq = idx & 15;
      int grow = rbase + r;
      float4 v = (grow < N) ? *(const float4*)&x[(size_t)grow * FIN + kc + kq * 4]
                            : make_float4(0.f, 0.f, 0.f, 0.f);
      unsigned p0 = (unsigned)f2b(v.x) | ((unsigned)f2b(v.y) << 16);
      unsigned p1 = (unsigned)f2b(v.z) | ((unsigned)f2b(v.w) << 16);
      *(uint2*)&xs[r * XPAD + kq * 4] = make_uint2(p0, p1);
    }
    __syncthreads();

    s16x8 a0  = *(const s16x8*)&xs[(wrow + m16) * XPAD + kg * 8];
    s16x8 a1  = *(const s16x8*)&xs[(wrow + m16) * XPAD + 32 + kg * 8];
    s16x8 b00 = *(const s16x8*)&wT[m16 * WPAD + kc + kg * 8];
    s16x8 b01 = *(const s16x8*)&wT[(16 + m16) * WPAD + kc + kg * 8];
    s16x8 b10 = *(const s16x8*)&wT[m16 * WPAD + kc + 32 + kg * 8];
    s16x8 b11 = *(const s16x8*)&wT[(16 + m16) * WPAD + kc + 32 + kg * 8];
    acc0 = __builtin_amdgcn_mfma_f32_16x16x32_bf16(a0, b00, acc0, 0, 0, 0);
    acc1 = __builtin_amdgcn_mfma_f32_16x16x32_bf16(a0, b01, acc1, 0, 0, 0);
    acc0 = __builtin_amdgcn_mfma_f32_16x16x32_bf16(a1, b10, acc0, 0, 0, 0);
    acc1 = __builtin_amdgcn_mfma_f32_16x16x32_bf16(a1, b11, acc1, 0, 0, 0);
  }

#pragma unroll
  for (int r = 0; r < 4; ++r) {
    int row = rbase + wrow + kg * 4 + r;
    if (row < N) {
      float dr = dis[row];
      h1b[(size_t)row * HD + m16]      = f2b(acc0[r] * dr);
      h1b[(size_t)row * HD + 16 + m16] = f2b(acc1[r] * dr);
    }
  }
}

// ---------------- layer1: edge-parallel LDS-agg pull + bias + relu + mm2 -> h2b ----------------
// 4 lanes/edge (uint4 = 16B of the 64B bf16 row): 16 edges per wave-instr,
// all gathers independent -> max MLP. agg rows padded to 33 floats.
__global__ __launch_bounds__(512) void k_pull1_mm2(const unsigned short* __restrict__ h1b,
                                                   const int* __restrict__ bin, const int* __restrict__ bbase,
                                                   const int* __restrict__ bcnt, const float* __restrict__ dis,
                                                   const float* __restrict__ b1, const float* __restrict__ W2,
                                                   unsigned short* __restrict__ h2b, int N) {
  __shared__ float agg[BN * AGP];  // 16.9 KB
  __shared__ float w[HD * HD];
  __shared__ float bb[HD];
  __shared__ float dl[BN];
  const int t = threadIdx.x;
  const int bkt = blockIdx.x;
  const int n0 = bkt * BN;
  int nn = N - n0; if (nn > BN) nn = BN;
  const int eb = bbase[bkt], ec = bcnt[bkt];

  if (t < HD) bb[t] = b1[t];
  for (int i = t; i < HD * HD; i += 512) w[i] = W2[i];
  if (t < nn) dl[t] = dis[n0 + t];
  for (int i = t; i < nn * HD; i += 512) {
    int r = i >> 5;
    agg[r * AGP + (i & 31)] = b2f(h1b[(size_t)(n0 + r) * HD + (i & 31)]);  // self term
  }
  __syncthreads();

  const int es = t >> 2, cg = t & 3;  // 128 edges per pass
  for (int j = es; j < ec; j += 128) {
    int e = bin[eb + j];
    int s = e & 0xFFFFF;
    int dr = (unsigned)e >> 20;
    uint4 u = *(const uint4*)&h1b[(size_t)s * HD + cg * 8];
    float* ap = &agg[dr * AGP + cg * 8];
    unsafeAtomicAdd(&ap[0], b2f_lo(u.x));
    unsafeAtomicAdd(&ap[1], b2f_hi(u.x));
    unsafeAtomicAdd(&ap[2], b2f_lo(u.y));
    unsafeAtomicAdd(&ap[3], b2f_hi(u.y));
    unsafeAtomicAdd(&ap[4], b2f_lo(u.z));
    unsafeAtomicAdd(&ap[5], b2f_hi(u.z));
    unsafeAtomicAdd(&ap[6], b2f_lo(u.w));
    unsafeAtomicAdd(&ap[7], b2f_hi(u.w));
  }
  __syncthreads();

  const int lane = t & 63, c = lane & 31;
  const int hw = (t >> 6) * 2 + (lane >> 5);  // 16 half-waves
  for (int r = hw; r < nn; r += 16) {
    float d = dl[r];
    float tv = fmaxf(fmaf(d, agg[r * AGP + c], bb[c]), 0.f);
    float a2 = 0.f;
#pragma unroll
    for (int k = 0; k < HD; ++k) a2 = fmaf(__shfl(tv, k, 32), w[k * HD + c], a2);
    h2b[(size_t)(n0 + r) * HD + c] = f2b(a2 * d);
  }
}

// ---------------- layer2: edge-parallel LDS-agg pull + bias + log_softmax -> out ----------------
__global__ __launch_bounds__(512) void k_pull2_lsm(const unsigned short* __restrict__ h2b,
                                                   const int* __restrict__ bin, const int* __restrict__ bbase,
                                                   const int* __restrict__ bcnt, const float* __restrict__ dis,
                                                   const float* __restrict__ b2, float* __restrict__ out, int N) {
  __shared__ float agg[BN * AGP];
  __shared__ float bb[HD];
  __shared__ float dl[BN];
  const int t = threadIdx.x;
  const int bkt = blockIdx.x;
  const int n0 = bkt * BN;
  int nn = N - n0; if (nn > BN) nn = BN;
  const int eb = bbase[bkt], ec = bcnt[bkt];

  if (t < HD) bb[t] = b2[t];
  if (t < nn) dl[t] = dis[n0 + t];
  for (int i = t; i < nn * HD; i += 512) {
    int r = i >> 5;
    agg[r * AGP + (i & 31)] = b2f(h2b[(size_t)(n0 + r) * HD + (i & 31)]);
  }
  __syncthreads();

  const int es = t >> 2, cg = t & 3;
  for (int j = es; j < ec; j += 128) {
    int e = bin[eb + j];
    int s = e & 0xFFFFF;
    int dr = (unsigned)e >> 20;
    uint4 u = *(const uint4*)&h2b[(size_t)s * HD + cg * 8];
    float* ap = &agg[dr * AGP + cg * 8];
    unsafeAtomicAdd(&ap[0], b2f_lo(u.x));
    unsafeAtomicAdd(&ap[1], b2f_hi(u.x));
    unsafeAtomicAdd(&ap[2], b2f_lo(u.y));
    unsafeAtomicAdd(&ap[3], b2f_hi(u.y));
    unsafeAtomicAdd(&ap[4], b2f_lo(u.z));
    unsafeAtomicAdd(&ap[5], b2f_hi(u.z));
    unsafeAtomicAdd(&ap[6], b2f_lo(u.w));
    unsafeAtomicAdd(&ap[7], b2f_hi(u.w));
  }
  __syncthreads();

  const int lane = t & 63, c = lane & 31;
  const int hw = (t >> 6) * 2 + (lane >> 5);
  for (int r = hw; r < nn; r += 16) {
    float v = fmaf(dl[r], agg[r * AGP + c], bb[c]);
    float m = v;
    for (int off = 16; off; off >>= 1) m = fmaxf(m, __shfl_xor(m, off, 32));
    float ex = __expf(v - m);
    float sm = ex;
    for (int off = 16; off; off >>= 1) sm += __shfl_xor(sm, off, 32);
    out[(size_t)(n0 + r) * HD + c] = v - m - __logf(sm);
  }
}

extern "C" void kernel_launch(void* const* d_in, const int* in_sizes, int n_in,
                              void* d_out, int out_size, void* d_ws, size_t ws_size,
                              hipStream_t stream) {
  const float* x  = (const float*)d_in[0];
  const int*   ei = (const int*)d_in[1];
  const float* W1 = (const float*)d_in[2];
  const float* b1 = (const float*)d_in[3];
  const float* W2 = (const float*)d_in[4];
  const float* b2 = (const float*)d_in[5];
  float* out = (float*)d_out;

  const int H   = in_sizes[3];            // 32
  const int Fin = in_sizes[2] / H;        // 512
  const int N   = in_sizes[0] / Fin;      // 100000
  const int E   = in_sizes[1] / 2;        // 3200000
  const int* src = ei;
  const int* dst = ei + E;
  const int B   = (N + BN - 1) / BN;      // 782 fine buckets

  char* wsp = (char*)d_ws;
  size_t off = 0;
  auto nxt = [&](size_t bytes) { char* p = wsp + off; off = (off + bytes + 255) & ~(size_t)255; return p; };
  int*   hist  = (int*)  nxt((size_t)NHB * NBP * 4);
  int*   bcnt  = (int*)  nxt(NBP * 4);
  int*   bbase = (int*)  nxt(NBP * 4);
  int*   bfill = (int*)  nxt(NBP * 4);
  float* dis   = (float*)nxt((size_t)N * 4);
  int*   bin   = (int*)  nxt((size_t)E * 4);
  unsigned short* h1b = (unsigned short*)nxt((size_t)N * HD * 2);
  unsigned short* h2b = (unsigned short*)nxt((size_t)N * HD * 2);
  (void)ws_size; (void)n_in; (void)out_size;

  k_bktcnt<<<NHB, 256, 0, stream>>>(dst, hist, E);
  k_bscan<<<1, 1024, 0, stream>>>(hist, bcnt, bbase, bfill, B);
  k_bin<<<(E + CH - 1) / CH, 512, 0, stream>>>(src, dst, bfill, bin, E);
  k_deg<<<B, 256, 0, stream>>>(bin, bbase, bcnt, dis, N);
  k_mm1<<<(N + 127) / 128, 512, 0, stream>>>(x, W1, dis, h1b, N);
  k_pull1_mm2<<<B, 512, 0, stream>>>(h1b, bin, bbase, bcnt, dis, b1, W2, h2b, N);
  k_pull2_lsm<<<B, 512, 0, stream>>>(h2b, bin, bbase, bcnt, dis, b2, out, N);
}

// Round 11
// 1496.643 us; speedup vs baseline: 1.0012x; 1.0012x over previous
//
#include <hip/hip_runtime.h>
#include <hip/hip_bf16.h>

#define FIN 512
#define HD 32
#define BN 128       // nodes per fine bucket (bucket = dst >> 7)
#define NB 782       // ceil(100000/128)
#define NBP 784      // padded
#define AGP 33       // agg row pad (33 floats) -> breaks bank degeneracy
#define CH 8192      // edges per bin chunk
#define NHB 128      // partial-histogram blocks

typedef short s16x8 __attribute__((ext_vector_type(8)));
typedef float f32x4 __attribute__((ext_vector_type(4)));

__device__ inline unsigned short f2b(float f) {  // fp32 -> bf16 bits, RNE
  unsigned u = __float_as_uint(f);
  return (unsigned short)((u + 0x7FFFu + ((u >> 16) & 1u)) >> 16);
}
__device__ inline float b2f(unsigned short b) {
  return __uint_as_float((unsigned)b << 16);
}
__device__ inline float b2f_lo(unsigned u) { return __uint_as_float(u << 16); }
__device__ inline float b2f_hi(unsigned u) { return __uint_as_float(u & 0xFFFF0000u); }

// ---------------- per-block partial histograms over dst>>7 (784 bins) ----------------
__global__ __launch_bounds__(256) void k_bktcnt(const int* __restrict__ dst, int* __restrict__ hist, int E) {
  __shared__ int h[NBP];
  int t = threadIdx.x;
  for (int b = t; b < NBP; b += 256) h[b] = 0;
  __syncthreads();
  for (int i = blockIdx.x * 256 + t; i < E; i += gridDim.x * 256)
    atomicAdd(&h[dst[i] >> 7], 1);
  __syncthreads();
  for (int b = t; b < NBP; b += 256) hist[blockIdx.x * NBP + b] = h[b];
}

// sum partials -> bcnt; exclusive scan -> bbase; init bfill
__global__ __launch_bounds__(1024) void k_bscan(const int* __restrict__ hist, int* __restrict__ bcnt,
                                                int* __restrict__ bbase, int* __restrict__ bfill, int B) {
  __shared__ int s[1024];
  int t = threadIdx.x;
  int v = 0;
  if (t < B)
    for (int b = 0; b < NHB; ++b) v += hist[b * NBP + t];
  s[t] = v;
  __syncthreads();
  for (int o = 1; o < 1024; o <<= 1) {
    int a = (t >= o) ? s[t - o] : 0;
    __syncthreads();
    s[t] += a;
    __syncthreads();
  }
  if (t < B) { bcnt[t] = v; bbase[t] = s[t] - v; bfill[t] = s[t] - v; }
}

// ---------------- fine binning: bin[] gets (src | dlow<<20) grouped by dst>>7 ----------------
__global__ __launch_bounds__(512) void k_bin(const int* __restrict__ src, const int* __restrict__ dst,
                                             int* __restrict__ bfill, int* __restrict__ bin, int E) {
  __shared__ int raw[CH];             // 32 KB
  __shared__ unsigned short bkt[CH];  // 16 KB
  __shared__ int cnt[NB];
  __shared__ int gbase[NB];
  int t = threadIdx.x;
  for (int cb = blockIdx.x * CH; cb < E; cb += gridDim.x * CH) {
    int n = E - cb; if (n > CH) n = CH;
    for (int b = t; b < NB; b += 512) cnt[b] = 0;
    __syncthreads();
    for (int j = t; j < n; j += 512) {
      int s = src[cb + j], d = dst[cb + j];
      raw[j] = s | ((d & 127) << 20);
      int b = d >> 7;
      bkt[j] = (unsigned short)b;
      atomicAdd(&cnt[b], 1);
    }
    __syncthreads();
    for (int b = t; b < NB; b += 512) {
      int c = cnt[b];
      gbase[b] = (c > 0) ? atomicAdd(&bfill[b], c) : 0;
      cnt[b] = 0;  // reuse as in-chunk cursor
    }
    __syncthreads();
    for (int j = t; j < n; j += 512) {
      int b = bkt[j];
      int r = atomicAdd(&cnt[b], 1);
      bin[gbase[b] + r] = raw[j];
    }
    __syncthreads();
  }
}

// ---------------- per-bucket degree -> dis ----------------
__global__ __launch_bounds__(256) void k_deg(const int* __restrict__ bin, const int* __restrict__ bbase,
                                             const int* __restrict__ bcnt, float* __restrict__ dis, int N) {
  __shared__ int cnt[BN];
  int t = threadIdx.x;
  int bkt = blockIdx.x, n0 = bkt * BN;
  int nn = N - n0; if (nn > BN) nn = BN;
  if (t < BN) cnt[t] = 0;
  __syncthreads();
  int eb = bbase[bkt], ec = bcnt[bkt];
  for (int j = t; j < ec; j += 256) atomicAdd(&cnt[(unsigned)bin[eb + j] >> 20], 1);
  __syncthreads();
  if (t < nn) dis[n0 + t] = rsqrtf((float)(cnt[t] + 1));
}

// ---------------- mm1 via MFMA: h1b = bf16((x @ W1) * dis[row]) ----------------
#define XPAD 72
#define WPAD 520
__global__ __launch_bounds__(512) void k_mm1(const float* __restrict__ x, const float* __restrict__ W1,
                                             const float* __restrict__ dis, unsigned short* __restrict__ h1b,
                                             int N) {
  __shared__ unsigned short wT[32 * WPAD];
  __shared__ unsigned short xs[128 * XPAD];
  const int t = threadIdx.x;
  const int rbase = blockIdx.x * 128;

  for (int idx = t; idx < FIN * HD; idx += 512) {
    int k = idx >> 5, c = idx & 31;
    wT[c * WPAD + k] = f2b(W1[idx]);
  }

  const int lane = t & 63;
  const int wrow = (t >> 6) * 16;
  const int m16 = lane & 15;
  const int kg = lane >> 4;

  f32x4 acc0 = {0.f, 0.f, 0.f, 0.f};
  f32x4 acc1 = {0.f, 0.f, 0.f, 0.f};

  for (int kc = 0; kc < FIN; kc += 64) {
    __syncthreads();
#pragma unroll
    for (int p = 0; p < 4; ++p) {
      int idx = p * 512 + t;
      int r = idx >> 4, kq = idx & 15;
      int grow = rbase + r;
      float4 v = (grow < N) ? *(const float4*)&x[(size_t)grow * FIN + kc + kq * 4]
                            : make_float4(0.f, 0.f, 0.f, 0.f);
      unsigned p0 = (unsigned)f2b(v.x) | ((unsigned)f2b(v.y) << 16);
      unsigned p1 = (unsigned)f2b(v.z) | ((unsigned)f2b(v.w) << 16);
      *(uint2*)&xs[r * XPAD + kq * 4] = make_uint2(p0, p1);
    }
    __syncthreads();

    s16x8 a0  = *(const s16x8*)&xs[(wrow + m16) * XPAD + kg * 8];
    s16x8 a1  = *(const s16x8*)&xs[(wrow + m16) * XPAD + 32 + kg * 8];
    s16x8 b00 = *(const s16x8*)&wT[m16 * WPAD + kc + kg * 8];
    s16x8 b01 = *(const s16x8*)&wT[(16 + m16) * WPAD + kc + kg * 8];
    s16x8 b10 = *(const s16x8*)&wT[m16 * WPAD + kc + 32 + kg * 8];
    s16x8 b11 = *(const s16x8*)&wT[(16 + m16) * WPAD + kc + 32 + kg * 8];
    acc0 = __builtin_amdgcn_mfma_f32_16x16x32_bf16(a0, b00, acc0, 0, 0, 0);
    acc1 = __builtin_amdgcn_mfma_f32_16x16x32_bf16(a0, b01, acc1, 0, 0, 0);
    acc0 = __builtin_amdgcn_mfma_f32_16x16x32_bf16(a1, b10, acc0, 0, 0, 0);
    acc1 = __builtin_amdgcn_mfma_f32_16x16x32_bf16(a1, b11, acc1, 0, 0, 0);
  }

#pragma unroll
  for (int r = 0; r < 4; ++r) {
    int row = rbase + wrow + kg * 4 + r;
    if (row < N) {
      float dr = dis[row];
      h1b[(size_t)row * HD + m16]      = f2b(acc0[r] * dr);
      h1b[(size_t)row * HD + 16 + m16] = f2b(acc1[r] * dr);
    }
  }
}

// ---------------- layer1: edge-parallel LDS-agg pull (ds_add_f32) + bias + relu + mm2 ----------------
__global__ __launch_bounds__(512) void k_pull1_mm2(const unsigned short* __restrict__ h1b,
                                                   const int* __restrict__ bin, const int* __restrict__ bbase,
                                                   const int* __restrict__ bcnt, const float* __restrict__ dis,
                                                   const float* __restrict__ b1, const float* __restrict__ W2,
                                                   unsigned short* __restrict__ h2b, int N) {
  __shared__ float agg[BN * AGP];  // 16.9 KB
  __shared__ float w[HD * HD];
  __shared__ float bb[HD];
  __shared__ float dl[BN];
  const int t = threadIdx.x;
  const int bkt = blockIdx.x;
  const int n0 = bkt * BN;
  int nn = N - n0; if (nn > BN) nn = BN;
  const int eb = bbase[bkt], ec = bcnt[bkt];

  if (t < HD) bb[t] = b1[t];
  for (int i = t; i < HD * HD; i += 512) w[i] = W2[i];
  if (t < nn) dl[t] = dis[n0 + t];
  for (int i = t; i < nn * HD; i += 512) {
    int r = i >> 5;
    agg[r * AGP + (i & 31)] = b2f(h1b[(size_t)(n0 + r) * HD + (i & 31)]);  // self term
  }
  __syncthreads();

  const int es = t >> 2, cg = t & 3;  // 128 edges per pass, 4 lanes/edge
  for (int j = es; j < ec; j += 128) {
    int e = bin[eb + j];
    int s = e & 0xFFFFF;
    int dr = (unsigned)e >> 20;
    uint4 u = *(const uint4*)&h1b[(size_t)s * HD + cg * 8];
    int base = dr * AGP + cg * 8;
    // direct atomicAdd on __shared__ -> addrspace(3) -> ds_add_f32 (NOT flat!)
    atomicAdd(&agg[base + 0], b2f_lo(u.x));
    atomicAdd(&agg[base + 1], b2f_hi(u.x));
    atomicAdd(&agg[base + 2], b2f_lo(u.y));
    atomicAdd(&agg[base + 3], b2f_hi(u.y));
    atomicAdd(&agg[base + 4], b2f_lo(u.z));
    atomicAdd(&agg[base + 5], b2f_hi(u.z));
    atomicAdd(&agg[base + 6], b2f_lo(u.w));
    atomicAdd(&agg[base + 7], b2f_hi(u.w));
  }
  __syncthreads();

  const int lane = t & 63, c = lane & 31;
  const int hw = (t >> 6) * 2 + (lane >> 5);  // 16 half-waves
  for (int r = hw; r < nn; r += 16) {
    float d = dl[r];
    float tv = fmaxf(fmaf(d, agg[r * AGP + c], bb[c]), 0.f);
    float a2 = 0.f;
#pragma unroll
    for (int k = 0; k < HD; ++k) a2 = fmaf(__shfl(tv, k, 32), w[k * HD + c], a2);
    h2b[(size_t)(n0 + r) * HD + c] = f2b(a2 * d);
  }
}

// ---------------- layer2: edge-parallel LDS-agg pull (ds_add_f32) + bias + log_softmax ----------------
__global__ __launch_bounds__(512) void k_pull2_lsm(const unsigned short* __restrict__ h2b,
                                                   const int* __restrict__ bin, const int* __restrict__ bbase,
                                                   const int* __restrict__ bcnt, const float* __restrict__ dis,
                                                   const float* __restrict__ b2, float* __restrict__ out, int N) {
  __shared__ float agg[BN * AGP];
  __shared__ float bb[HD];
  __shared__ float dl[BN];
  const int t = threadIdx.x;
  const int bkt = blockIdx.x;
  const int n0 = bkt * BN;
  int nn = N - n0; if (nn > BN) nn = BN;
  const int eb = bbase[bkt], ec = bcnt[bkt];

  if (t < HD) bb[t] = b2[t];
  if (t < nn) dl[t] = dis[n0 + t];
  for (int i = t; i < nn * HD; i += 512) {
    int r = i >> 5;
    agg[r * AGP + (i & 31)] = b2f(h2b[(size_t)(n0 + r) * HD + (i & 31)]);
  }
  __syncthreads();

  const int es = t >> 2, cg = t & 3;
  for (int j = es; j < ec; j += 128) {
    int e = bin[eb + j];
    int s = e & 0xFFFFF;
    int dr = (unsigned)e >> 20;
    uint4 u = *(const uint4*)&h2b[(size_t)s * HD + cg * 8];
    int base = dr * AGP + cg * 8;
    atomicAdd(&agg[base + 0], b2f_lo(u.x));
    atomicAdd(&agg[base + 1], b2f_hi(u.x));
    atomicAdd(&agg[base + 2], b2f_lo(u.y));
    atomicAdd(&agg[base + 3], b2f_hi(u.y));
    atomicAdd(&agg[base + 4], b2f_lo(u.z));
    atomicAdd(&agg[base + 5], b2f_hi(u.z));
    atomicAdd(&agg[base + 6], b2f_lo(u.w));
    atomicAdd(&agg[base + 7], b2f_hi(u.w));
  }
  __syncthreads();

  const int lane = t & 63, c = lane & 31;
  const int hw = (t >> 6) * 2 + (lane >> 5);
  for (int r = hw; r < nn; r += 16) {
    float v = fmaf(dl[r], agg[r * AGP + c], bb[c]);
    float m = v;
    for (int off = 16; off; off >>= 1) m = fmaxf(m, __shfl_xor(m, off, 32));
    float ex = __expf(v - m);
    float sm = ex;
    for (int off = 16; off; off >>= 1) sm += __shfl_xor(sm, off, 32);
    out[(size_t)(n0 + r) * HD + c] = v - m - __logf(sm);
  }
}

extern "C" void kernel_launch(void* const* d_in, const int* in_sizes, int n_in,
                              void* d_out, int out_size, void* d_ws, size_t ws_size,
                              hipStream_t stream) {
  const float* x  = (const float*)d_in[0];
  const int*   ei = (const int*)d_in[1];
  const float* W1 = (const float*)d_in[2];
  const float* b1 = (const float*)d_in[3];
  const float* W2 = (const float*)d_in[4];
  const float* b2 = (const float*)d_in[5];
  float* out = (float*)d_out;

  const int H   = in_sizes[3];            // 32
  const int Fin = in_sizes[2] / H;        // 512
  const int N   = in_sizes[0] / Fin;      // 100000
  const int E   = in_sizes[1] / 2;        // 3200000
  const int* src = ei;
  const int* dst = ei + E;
  const int B   = (N + BN - 1) / BN;      // 782 fine buckets

  char* wsp = (char*)d_ws;
  size_t off = 0;
  auto nxt = [&](size_t bytes) { char* p = wsp + off; off = (off + bytes + 255) & ~(size_t)255; return p; };
  int*   hist  = (int*)  nxt((size_t)NHB * NBP * 4);
  int*   bcnt  = (int*)  nxt(NBP * 4);
  int*   bbase = (int*)  nxt(NBP * 4);
  int*   bfill = (int*)  nxt(NBP * 4);
  float* dis   = (float*)nxt((size_t)N * 4);
  int*   bin   = (int*)  nxt((size_t)E * 4);
  unsigned short* h1b = (unsigned short*)nxt((size_t)N * HD * 2);
  unsigned short* h2b = (unsigned short*)nxt((size_t)N * HD * 2);
  (void)ws_size; (void)n_in; (void)out_size;

  k_bktcnt<<<NHB, 256, 0, stream>>>(dst, hist, E);
  k_bscan<<<1, 1024, 0, stream>>>(hist, bcnt, bbase, bfill, B);
  k_bin<<<(E + CH - 1) / CH, 512, 0, stream>>>(src, dst, bfill, bin, E);
  k_deg<<<B, 256, 0, stream>>>(bin, bbase, bcnt, dis, N);
  k_mm1<<<(N + 127) / 128, 512, 0, stream>>>(x, W1, dis, h1b, N);
  k_pull1_mm2<<<B, 512, 0, stream>>>(h1b, bin, bbase, bcnt, dis, b1, W2, h2b, N);
  k_pull2_lsm<<<B, 512, 0, stream>>>(h2b, bin, bbase, bcnt, dis, b2, out, N);
}

// Round 12
// 272.738 us; speedup vs baseline: 5.4939x; 5.4875x over previous
//
#include <hip/hip_runtime.h>
#include <hip/hip_bf16.h>

#define FIN 512
#define HD 32
#define BNODES 512   // nodes per dst-bucket (bucket = dst >> 9)
#define CH 8192      // edges per bin chunk
#define NHB 128      // partial-histogram blocks

typedef short s16x8 __attribute__((ext_vector_type(8)));
typedef float f32x4 __attribute__((ext_vector_type(4)));

__device__ inline unsigned short f2b(float f) {  // fp32 -> bf16 bits, RNE
  unsigned u = __float_as_uint(f);
  return (unsigned short)((u + 0x7FFFu + ((u >> 16) & 1u)) >> 16);
}
__device__ inline float b2f(unsigned short b) {
  return __uint_as_float((unsigned)b << 16);
}
__device__ inline float b2f_lo(unsigned u) { return __uint_as_float(u << 16); }
__device__ inline float b2f_hi(unsigned u) { return __uint_as_float(u & 0xFFFF0000u); }

// ---------------- per-block partial histograms over dst>>9 ----------------
__global__ __launch_bounds__(256) void k_bktcnt(const int* __restrict__ dst, int* __restrict__ hist, int E) {
  __shared__ int h[256];
  int t = threadIdx.x;
  h[t] = 0;
  __syncthreads();
  for (int i = blockIdx.x * 256 + t; i < E; i += gridDim.x * 256)
    atomicAdd(&h[dst[i] >> 9], 1);
  __syncthreads();
  hist[blockIdx.x * 256 + t] = h[t];
}

// sum partials -> bcnt; exclusive scan -> bbase; init bfill
__global__ __launch_bounds__(256) void k_bscan(const int* __restrict__ hist, int* __restrict__ bcnt,
                                               int* __restrict__ bbase, int* __restrict__ bfill) {
  __shared__ int s[256];
  int t = threadIdx.x;
  int v = 0;
  for (int b = 0; b < NHB; ++b) v += hist[b * 256 + t];
  bcnt[t] = v;
  s[t] = v;
  __syncthreads();
  for (int o = 1; o < 256; o <<= 1) {
    int a = (t >= o) ? s[t - o] : 0;
    __syncthreads();
    s[t] += a;
    __syncthreads();
  }
  bbase[t] = s[t] - v;
  bfill[t] = s[t] - v;
}

// ---------------- phase 1: coarse bin, packed 4B entries (src | dlow<<22) ----------------
__global__ __launch_bounds__(512) void k_bin(const int* __restrict__ src, const int* __restrict__ dst,
                                             int* __restrict__ bfill, int* __restrict__ bin, int E) {
  __shared__ int raw[CH];
  __shared__ unsigned char bkt[CH];
  __shared__ int cnt[256];
  __shared__ int gbase[256];
  int t = threadIdx.x;
  for (int cb = blockIdx.x * CH; cb < E; cb += gridDim.x * CH) {
    int n = E - cb; if (n > CH) n = CH;
    if (t < 256) cnt[t] = 0;
    __syncthreads();
    for (int j = t; j < n; j += 512) {
      int s = src[cb + j], d = dst[cb + j];
      raw[j] = s | ((d & 511) << 22);
      bkt[j] = (unsigned char)(d >> 9);
      atomicAdd(&cnt[d >> 9], 1);
    }
    __syncthreads();
    if (t < 256) {
      int c = cnt[t];
      gbase[t] = (c > 0) ? atomicAdd(&bfill[t], c) : 0;
      cnt[t] = 0;
    }
    __syncthreads();
    for (int j = t; j < n; j += 512) {
      int b = bkt[j];
      int r = atomicAdd(&cnt[b], 1);
      bin[gbase[b] + r] = raw[j];
    }
    __syncthreads();
  }
}

// ---------------- phase 2: per-bucket exact CSR (src-only) + deg/dis/offsets ----------------
__global__ __launch_bounds__(512) void k_csr(const int* __restrict__ bin, const int* __restrict__ bbase,
                                             const int* __restrict__ bcnt, int* __restrict__ cntm1,
                                             float* __restrict__ dis, int* __restrict__ offsets,
                                             int* __restrict__ csr, int N) {
  __shared__ int cnt[BNODES];
  __shared__ int sc[BNODES];
  const int t = threadIdx.x;
  const int bkt = blockIdx.x;
  const int n0 = bkt * BNODES;
  int nn = N - n0; if (nn > BNODES) nn = BNODES;
  const int eb = bbase[bkt], ec = bcnt[bkt];

  cnt[t] = 0;
  __syncthreads();
  for (int j = t; j < ec; j += 512)
    atomicAdd(&cnt[(unsigned)bin[eb + j] >> 22], 1);
  __syncthreads();
  int v = cnt[t];
  if (t < nn) {
    cntm1[n0 + t] = v;
    dis[n0 + t] = rsqrtf((float)(v + 1));
  }
  sc[t] = v;
  __syncthreads();
  for (int o = 1; o < 512; o <<= 1) {
    int a = (t >= o) ? sc[t - o] : 0;
    __syncthreads();
    sc[t] += a;
    __syncthreads();
  }
  int myoff = sc[t] - v;
  if (t < nn) offsets[n0 + t] = eb + myoff;
  cnt[t] = myoff;
  __syncthreads();
  for (int j = t; j < ec; j += 512) {
    int e = bin[eb + j];
    int pos = atomicAdd(&cnt[(unsigned)e >> 22], 1);
    csr[eb + pos] = e & 0x3FFFFF;
  }
}

// ---------------- mm1 via MFMA: h1b = bf16((x @ W1) * dis[row]) ----------------
#define XPAD 72
#define WPAD 520
__global__ __launch_bounds__(512) void k_mm1(const float* __restrict__ x, const float* __restrict__ W1,
                                             const float* __restrict__ dis, unsigned short* __restrict__ h1b,
                                             int N) {
  __shared__ unsigned short wT[32 * WPAD];
  __shared__ unsigned short xs[128 * XPAD];
  const int t = threadIdx.x;
  const int rbase = blockIdx.x * 128;

  for (int idx = t; idx < FIN * HD; idx += 512) {
    int k = idx >> 5, c = idx & 31;
    wT[c * WPAD + k] = f2b(W1[idx]);
  }

  const int lane = t & 63;
  const int wrow = (t >> 6) * 16;
  const int m16 = lane & 15;
  const int kg = lane >> 4;

  f32x4 acc0 = {0.f, 0.f, 0.f, 0.f};
  f32x4 acc1 = {0.f, 0.f, 0.f, 0.f};

  for (int kc = 0; kc < FIN; kc += 64) {
    __syncthreads();
#pragma unroll
    for (int p = 0; p < 4; ++p) {
      int idx = p * 512 + t;
      int r = idx >> 4, kq = idx & 15;
      int grow = rbase + r;
      float4 v = (grow < N) ? *(const float4*)&x[(size_t)grow * FIN + kc + kq * 4]
                            : make_float4(0.f, 0.f, 0.f, 0.f);
      unsigned p0 = (unsigned)f2b(v.x) | ((unsigned)f2b(v.y) << 16);
      unsigned p1 = (unsigned)f2b(v.z) | ((unsigned)f2b(v.w) << 16);
      *(uint2*)&xs[r * XPAD + kq * 4] = make_uint2(p0, p1);
    }
    __syncthreads();

    s16x8 a0  = *(const s16x8*)&xs[(wrow + m16) * XPAD + kg * 8];
    s16x8 a1  = *(const s16x8*)&xs[(wrow + m16) * XPAD + 32 + kg * 8];
    s16x8 b00 = *(const s16x8*)&wT[m16 * WPAD + kc + kg * 8];
    s16x8 b01 = *(const s16x8*)&wT[(16 + m16) * WPAD + kc + kg * 8];
    s16x8 b10 = *(const s16x8*)&wT[m16 * WPAD + kc + 32 + kg * 8];
    s16x8 b11 = *(const s16x8*)&wT[(16 + m16) * WPAD + kc + 32 + kg * 8];
    acc0 = __builtin_amdgcn_mfma_f32_16x16x32_bf16(a0, b00, acc0, 0, 0, 0);
    acc1 = __builtin_amdgcn_mfma_f32_16x16x32_bf16(a0, b01, acc1, 0, 0, 0);
    acc0 = __builtin_amdgcn_mfma_f32_16x16x32_bf16(a1, b10, acc0, 0, 0, 0);
    acc1 = __builtin_amdgcn_mfma_f32_16x16x32_bf16(a1, b11, acc1, 0, 0, 0);
  }

#pragma unroll
  for (int r = 0; r < 4; ++r) {
    int row = rbase + wrow + kg * 4 + r;
    if (row < N) {
      float dr = dis[row];
      h1b[(size_t)row * HD + m16]      = f2b(acc0[r] * dr);
      h1b[(size_t)row * HD + 16 + m16] = f2b(acc1[r] * dr);
    }
  }
}

// ---------------- pair-row wide-gather pull core ----------------
// Two adjacent rows per half-wave, interleaved 8-edge x 16B gather groups:
// 2x independent gather chains in flight vs R9's single chain.
__device__ inline void pull_pair(const unsigned short* __restrict__ h, const int* __restrict__ csr,
                                 int jb0, int c0, int jb1, int c1, int L, int es, int cg,
                                 float& out0, float& out1) {
  float a0 = 0.f, a1 = 0.f, a2 = 0.f, a3 = 0.f, a4 = 0.f, a5 = 0.f, a6 = 0.f, a7 = 0.f;
  float b0 = 0.f, b1 = 0.f, b2 = 0.f, b3 = 0.f, b4 = 0.f, b5 = 0.f, b6 = 0.f, b7 = 0.f;
  int mx = max(c0, c1);
  for (int j = 0; j < mx; j += 8) {
    int eidx = j + es;
    if (j < c0) {  // uniform within half-wave
      int sidx = csr[jb0 + min(eidx, c0 - 1)];
      uint4 u = *(const uint4*)&h[(size_t)sidx * HD + cg * 8];
      if (eidx >= c0) u = make_uint4(0, 0, 0, 0);
      a0 += b2f_lo(u.x); a1 += b2f_hi(u.x);
      a2 += b2f_lo(u.y); a3 += b2f_hi(u.y);
      a4 += b2f_lo(u.z); a5 += b2f_hi(u.z);
      a6 += b2f_lo(u.w); a7 += b2f_hi(u.w);
    }
    if (j < c1) {
      int sidx = csr[jb1 + min(eidx, c1 - 1)];
      uint4 u = *(const uint4*)&h[(size_t)sidx * HD + cg * 8];
      if (eidx >= c1) u = make_uint4(0, 0, 0, 0);
      b0 += b2f_lo(u.x); b1 += b2f_hi(u.x);
      b2 += b2f_lo(u.y); b3 += b2f_hi(u.y);
      b4 += b2f_lo(u.z); b5 += b2f_hi(u.z);
      b6 += b2f_lo(u.w); b7 += b2f_hi(u.w);
    }
  }
#pragma unroll
  for (int o = 4; o <= 16; o <<= 1) {
    a0 += __shfl_xor(a0, o, 32); a1 += __shfl_xor(a1, o, 32);
    a2 += __shfl_xor(a2, o, 32); a3 += __shfl_xor(a3, o, 32);
    a4 += __shfl_xor(a4, o, 32); a5 += __shfl_xor(a5, o, 32);
    a6 += __shfl_xor(a6, o, 32); a7 += __shfl_xor(a7, o, 32);
    b0 += __shfl_xor(b0, o, 32); b1 += __shfl_xor(b1, o, 32);
    b2 += __shfl_xor(b2, o, 32); b3 += __shfl_xor(b3, o, 32);
    b4 += __shfl_xor(b4, o, 32); b5 += __shfl_xor(b5, o, 32);
    b6 += __shfl_xor(b6, o, 32); b7 += __shfl_xor(b7, o, 32);
  }
  int srcl = L >> 3;
  int sel = L & 7;
  float s0 = __shfl(a0, srcl, 32);
  float s1 = __shfl(b0, srcl, 32);
  float c;
  c = __shfl(a1, srcl, 32); s0 = (sel == 1) ? c : s0;
  c = __shfl(a2, srcl, 32); s0 = (sel == 2) ? c : s0;
  c = __shfl(a3, srcl, 32); s0 = (sel == 3) ? c : s0;
  c = __shfl(a4, srcl, 32); s0 = (sel == 4) ? c : s0;
  c = __shfl(a5, srcl, 32); s0 = (sel == 5) ? c : s0;
  c = __shfl(a6, srcl, 32); s0 = (sel == 6) ? c : s0;
  c = __shfl(a7, srcl, 32); s0 = (sel == 7) ? c : s0;
  c = __shfl(b1, srcl, 32); s1 = (sel == 1) ? c : s1;
  c = __shfl(b2, srcl, 32); s1 = (sel == 2) ? c : s1;
  c = __shfl(b3, srcl, 32); s1 = (sel == 3) ? c : s1;
  c = __shfl(b4, srcl, 32); s1 = (sel == 4) ? c : s1;
  c = __shfl(b5, srcl, 32); s1 = (sel == 5) ? c : s1;
  c = __shfl(b6, srcl, 32); s1 = (sel == 6) ? c : s1;
  c = __shfl(b7, srcl, 32); s1 = (sel == 7) ? c : s1;
  out0 = s0;
  out1 = s1;
}

// ---------------- layer1: pair-row wide pull + bias + relu + mm2 -> h2b ----------------
__global__ __launch_bounds__(256) void k_pull1_mm2(const unsigned short* __restrict__ h1b,
                                                   const int* __restrict__ csr, const int* __restrict__ offsets,
                                                   const int* __restrict__ cntm1, const float* __restrict__ dis,
                                                   const float* __restrict__ b1, const float* __restrict__ W2,
                                                   unsigned short* __restrict__ h2b, int N) {
  __shared__ float w[HD * HD];
  __shared__ float bb[HD];
  int t = threadIdx.x;
  if (t < HD) bb[t] = b1[t];
  for (int i = t; i < HD * HD; i += 256) w[i] = W2[i];
  __syncthreads();

  int lane = t & 63, L = lane & 31;
  int es = L >> 2, cg = L & 3;
  int halfId = (blockIdx.x * 4 + (t >> 6)) * 2 + (lane >> 5);
  int stride2 = gridDim.x * 16;
  for (int i0 = halfId * 2; i0 < N; i0 += stride2) {
    int i1 = i0 + 1;
    bool has1 = i1 < N;
    float sum0, sum1;
    pull_pair(h1b, csr, offsets[i0], cntm1[i0], has1 ? offsets[i1] : offsets[i0],
              has1 ? cntm1[i1] : 0, L, es, cg, sum0, sum1);
    sum0 += b2f(h1b[(size_t)i0 * HD + L]);                      // self
    sum1 += has1 ? b2f(h1b[(size_t)i1 * HD + L]) : 0.f;
    float d0 = dis[i0];
    float d1 = has1 ? dis[i1] : 0.f;
    float tv0 = fmaxf(fmaf(d0, sum0, bb[L]), 0.f);
    float tv1 = fmaxf(fmaf(d1, sum1, bb[L]), 0.f);
    float a20 = 0.f, a21 = 0.f;
#pragma unroll
    for (int k = 0; k < HD; ++k) {
      float wk = w[k * HD + L];
      a20 = fmaf(__shfl(tv0, k, 32), wk, a20);
      a21 = fmaf(__shfl(tv1, k, 32), wk, a21);
    }
    h2b[(size_t)i0 * HD + L] = f2b(a20 * d0);
    if (has1) h2b[(size_t)i1 * HD + L] = f2b(a21 * d1);
  }
}

// ---------------- layer2: pair-row wide pull + bias + log_softmax -> out ----------------
__global__ __launch_bounds__(256) void k_pull2_lsm(const unsigned short* __restrict__ h2b,
                                                   const int* __restrict__ csr, const int* __restrict__ offsets,
                                                   const int* __restrict__ cntm1, const float* __restrict__ dis,
                                                   const float* __restrict__ b2, float* __restrict__ out, int N) {
  __shared__ float bb[HD];
  int t = threadIdx.x;
  if (t < HD) bb[t] = b2[t];
  __syncthreads();

  int lane = t & 63, L = lane & 31;
  int es = L >> 2, cg = L & 3;
  int halfId = (blockIdx.x * 4 + (t >> 6)) * 2 + (lane >> 5);
  int stride2 = gridDim.x * 16;
  for (int i0 = halfId * 2; i0 < N; i0 += stride2) {
    int i1 = i0 + 1;
    bool has1 = i1 < N;
    float sum0, sum1;
    pull_pair(h2b, csr, offsets[i0], cntm1[i0], has1 ? offsets[i1] : offsets[i0],
              has1 ? cntm1[i1] : 0, L, es, cg, sum0, sum1);
    sum0 += b2f(h2b[(size_t)i0 * HD + L]);
    sum1 += has1 ? b2f(h2b[(size_t)i1 * HD + L]) : 0.f;
    float v0 = fmaf(dis[i0], sum0, bb[L]);
    float v1 = has1 ? fmaf(dis[i1], sum1, bb[L]) : 0.f;
    float m0 = v0, m1 = v1;
    for (int off = 16; off; off >>= 1) {
      m0 = fmaxf(m0, __shfl_xor(m0, off, 32));
      m1 = fmaxf(m1, __shfl_xor(m1, off, 32));
    }
    float e0 = __expf(v0 - m0), e1 = __expf(v1 - m1);
    float sm0 = e0, sm1 = e1;
    for (int off = 16; off; off >>= 1) {
      sm0 += __shfl_xor(sm0, off, 32);
      sm1 += __shfl_xor(sm1, off, 32);
    }
    out[(size_t)i0 * HD + L] = v0 - m0 - __logf(sm0);
    if (has1) out[(size_t)i1 * HD + L] = v1 - m1 - __logf(sm1);
  }
}

extern "C" void kernel_launch(void* const* d_in, const int* in_sizes, int n_in,
                              void* d_out, int out_size, void* d_ws, size_t ws_size,
                              hipStream_t stream) {
  const float* x  = (const float*)d_in[0];
  const int*   ei = (const int*)d_in[1];
  const float* W1 = (const float*)d_in[2];
  const float* b1 = (const float*)d_in[3];
  const float* W2 = (const float*)d_in[4];
  const float* b2 = (const float*)d_in[5];
  float* out = (float*)d_out;

  const int H   = in_sizes[3];            // 32
  const int Fin = in_sizes[2] / H;        // 512
  const int N   = in_sizes[0] / Fin;      // 100000
  const int E   = in_sizes[1] / 2;        // 3200000
  const int* src = ei;
  const int* dst = ei + E;
  const int B   = (N + BNODES - 1) / BNODES;  // 196 buckets

  char* wsp = (char*)d_ws;
  size_t off = 0;
  auto nxt = [&](size_t bytes) { char* p = wsp + off; off = (off + bytes + 255) & ~(size_t)255; return p; };
  int*   hist    = (int*)  nxt((size_t)NHB * 256 * 4);
  int*   bcnt    = (int*)  nxt(256 * 4);
  int*   bbase   = (int*)  nxt(256 * 4);
  int*   bfill   = (int*)  nxt(256 * 4);
  int*   cntm1   = (int*)  nxt((size_t)N * 4);
  float* dis     = (float*)nxt((size_t)N * 4);
  int*   offsets = (int*)  nxt((size_t)N * 4);
  int*   bin     = (int*)  nxt((size_t)E * 4);
  int*   csr     = (int*)  nxt((size_t)E * 4);
  unsigned short* h1b = (unsigned short*)nxt((size_t)N * HD * 2);
  unsigned short* h2b = (unsigned short*)nxt((size_t)N * HD * 2);
  (void)ws_size; (void)n_in; (void)out_size;

  k_bktcnt<<<NHB, 256, 0, stream>>>(dst, hist, E);
  k_bscan<<<1, 256, 0, stream>>>(hist, bcnt, bbase, bfill);
  k_bin<<<(E + CH - 1) / CH, 512, 0, stream>>>(src, dst, bfill, bin, E);
  k_csr<<<B, 512, 0, stream>>>(bin, bbase, bcnt, cntm1, dis, offsets, csr, N);
  k_mm1<<<(N + 127) / 128, 512, 0, stream>>>(x, W1, dis, h1b, N);
  k_pull1_mm2<<<2048, 256, 0, stream>>>(h1b, csr, offsets, cntm1, dis, b1, W2, h2b, N);
  k_pull2_lsm<<<2048, 256, 0, stream>>>(h2b, csr, offsets, cntm1, dis, b2, out, N);
}

// Round 14
// 230.193 us; speedup vs baseline: 6.5093x; 1.1848x over previous
//
#include <hip/hip_runtime.h>
#include <hip/hip_bf16.h>

#define FIN 512
#define HD 32
#define BNODES 512   // nodes per dst-bucket (bucket = dst >> 9)
#define CH 8192      // edges per bin chunk
#define NHB 128      // partial-histogram blocks

typedef short s16x8 __attribute__((ext_vector_type(8)));
typedef float f32x4 __attribute__((ext_vector_type(4)));

__device__ inline unsigned short f2b(float f) {  // fp32 -> bf16 bits, RNE
  unsigned u = __float_as_uint(f);
  return (unsigned short)((u + 0x7FFFu + ((u >> 16) & 1u)) >> 16);
}
__device__ inline float b2f(unsigned short b) {
  return __uint_as_float((unsigned)b << 16);
}
__device__ inline float b2f_lo(unsigned u) { return __uint_as_float(u << 16); }
__device__ inline float b2f_hi(unsigned u) { return __uint_as_float(u & 0xFFFF0000u); }

// ---------------- per-block partial histograms over dst>>9 ----------------
__global__ __launch_bounds__(256) void k_bktcnt(const int* __restrict__ dst, int* __restrict__ hist, int E) {
  __shared__ int h[256];
  int t = threadIdx.x;
  h[t] = 0;
  __syncthreads();
  for (int i = blockIdx.x * 256 + t; i < E; i += gridDim.x * 256)
    atomicAdd(&h[dst[i] >> 9], 1);
  __syncthreads();
  hist[blockIdx.x * 256 + t] = h[t];
}

__global__ __launch_bounds__(256) void k_bscan(const int* __restrict__ hist, int* __restrict__ bcnt,
                                               int* __restrict__ bbase, int* __restrict__ bfill) {
  __shared__ int s[256];
  int t = threadIdx.x;
  int v = 0;
  for (int b = 0; b < NHB; ++b) v += hist[b * 256 + t];
  bcnt[t] = v;
  s[t] = v;
  __syncthreads();
  for (int o = 1; o < 256; o <<= 1) {
    int a = (t >= o) ? s[t - o] : 0;
    __syncthreads();
    s[t] += a;
    __syncthreads();
  }
  bbase[t] = s[t] - v;
  bfill[t] = s[t] - v;
}

// ---------------- fused: [coarse bin] || [mm1 unscaled] ----------------
#define XPAD 72
#define WPAD 520
#define SMEM_BYTES 51712
__global__ __launch_bounds__(512) void k_fused(const int* __restrict__ src, const int* __restrict__ dst,
                                               int* __restrict__ bfill, int* __restrict__ bin, int E, int NBIN,
                                               const float* __restrict__ x, const float* __restrict__ W1,
                                               unsigned short* __restrict__ h1u, int N) {
  __shared__ __align__(16) char smem[SMEM_BYTES];
  const int t = threadIdx.x;

  if (blockIdx.x < NBIN) {
    // ---- bin branch: one chunk ----
    int* raw = (int*)smem;                                   // 32768 B
    unsigned short* bkt = (unsigned short*)(smem + 32768);   // 16384 B
    int* cnt = (int*)(smem + 49152);                         // 1024 B
    int* gbase = (int*)(smem + 50176);                       // 1024 B
    int cb = blockIdx.x * CH;
    int n = E - cb; if (n > CH) n = CH;
    if (t < 256) cnt[t] = 0;
    __syncthreads();
    for (int j = t; j < n; j += 512) {
      int s = src[cb + j], d = dst[cb + j];
      raw[j] = s | ((d & 511) << 22);
      bkt[j] = (unsigned short)(d >> 9);
      atomicAdd(&cnt[d >> 9], 1);
    }
    __syncthreads();
    if (t < 256) {
      int c = cnt[t];
      gbase[t] = (c > 0) ? atomicAdd(&bfill[t], c) : 0;
      cnt[t] = 0;
    }
    __syncthreads();
    for (int j = t; j < n; j += 512) {
      int b = bkt[j];
      int r = atomicAdd(&cnt[b], 1);
      bin[gbase[b] + r] = raw[j];
    }
  } else {
    // ---- mm1u branch: h1u = bf16(x @ W1), no dis scaling yet ----
    unsigned short* wT = (unsigned short*)smem;              // 33280 B
    unsigned short* xs = (unsigned short*)(smem + 33280);    // 18432 B
    const int rbase = (blockIdx.x - NBIN) * 128;

    for (int idx = t; idx < FIN * HD; idx += 512) {
      int k = idx >> 5, c = idx & 31;
      wT[c * WPAD + k] = f2b(W1[idx]);
    }

    const int lane = t & 63;
    const int wrow = (t >> 6) * 16;
    const int m16 = lane & 15;
    const int kg = lane >> 4;

    f32x4 acc0 = {0.f, 0.f, 0.f, 0.f};
    f32x4 acc1 = {0.f, 0.f, 0.f, 0.f};

    for (int kc = 0; kc < FIN; kc += 64) {
      __syncthreads();
#pragma unroll
      for (int p = 0; p < 4; ++p) {
        int idx = p * 512 + t;
        int r = idx >> 4, kq = idx & 15;
        int grow = rbase + r;
        float4 v = (grow < N) ? *(const float4*)&x[(size_t)grow * FIN + kc + kq * 4]
                              : make_float4(0.f, 0.f, 0.f, 0.f);
        unsigned p0 = (unsigned)f2b(v.x) | ((unsigned)f2b(v.y) << 16);
        unsigned p1 = (unsigned)f2b(v.z) | ((unsigned)f2b(v.w) << 16);
        *(uint2*)&xs[r * XPAD + kq * 4] = make_uint2(p0, p1);
      }
      __syncthreads();

      s16x8 a0  = *(const s16x8*)&xs[(wrow + m16) * XPAD + kg * 8];
      s16x8 a1  = *(const s16x8*)&xs[(wrow + m16) * XPAD + 32 + kg * 8];
      s16x8 b00 = *(const s16x8*)&wT[m16 * WPAD + kc + kg * 8];
      s16x8 b01 = *(const s16x8*)&wT[(16 + m16) * WPAD + kc + kg * 8];
      s16x8 b10 = *(const s16x8*)&wT[m16 * WPAD + kc + 32 + kg * 8];
      s16x8 b11 = *(const s16x8*)&wT[(16 + m16) * WPAD + kc + 32 + kg * 8];
      acc0 = __builtin_amdgcn_mfma_f32_16x16x32_bf16(a0, b00, acc0, 0, 0, 0);
      acc1 = __builtin_amdgcn_mfma_f32_16x16x32_bf16(a0, b01, acc1, 0, 0, 0);
      acc0 = __builtin_amdgcn_mfma_f32_16x16x32_bf16(a1, b10, acc0, 0, 0, 0);
      acc1 = __builtin_amdgcn_mfma_f32_16x16x32_bf16(a1, b11, acc1, 0, 0, 0);
    }

#pragma unroll
    for (int r = 0; r < 4; ++r) {
      int row = rbase + wrow + kg * 4 + r;
      if (row < N) {
        h1u[(size_t)row * HD + m16]      = f2b(acc0[r]);
        h1u[(size_t)row * HD + 16 + m16] = f2b(acc1[r]);
      }
    }
  }
}

// ---------------- per-bucket exact CSR + deg/dis/offsets + h1 scale ----------------
__global__ __launch_bounds__(512) void k_csr(const int* __restrict__ bin, const int* __restrict__ bbase,
                                             const int* __restrict__ bcnt, int* __restrict__ cntm1,
                                             float* __restrict__ dis, int* __restrict__ offsets,
                                             int* __restrict__ csr, const unsigned short* __restrict__ h1u,
                                             unsigned short* __restrict__ h1b, int N) {
  __shared__ int cnt[BNODES];
  __shared__ int sc[BNODES];
  __shared__ float disl[BNODES];
  const int t = threadIdx.x;
  const int bkt = blockIdx.x;
  const int n0 = bkt * BNODES;
  int nn = N - n0; if (nn > BNODES) nn = BNODES;
  const int eb = bbase[bkt], ec = bcnt[bkt];

  cnt[t] = 0;
  __syncthreads();
  for (int j = t; j < ec; j += 512)
    atomicAdd(&cnt[(unsigned)bin[eb + j] >> 22], 1);
  __syncthreads();
  int v = cnt[t];
  float dv = rsqrtf((float)(v + 1));
  if (t < nn) {
    cntm1[n0 + t] = v;
    dis[n0 + t] = dv;
    disl[t] = dv;
  }
  sc[t] = v;
  __syncthreads();
  for (int o = 1; o < 512; o <<= 1) {
    int a = (t >= o) ? sc[t - o] : 0;
    __syncthreads();
    sc[t] += a;
    __syncthreads();
  }
  int myoff = sc[t] - v;
  if (t < nn) offsets[n0 + t] = eb + myoff;
  cnt[t] = myoff;
  __syncthreads();
  for (int j = t; j < ec; j += 512) {
    int e = bin[eb + j];
    int pos = atomicAdd(&cnt[(unsigned)e >> 22], 1);
    csr[eb + pos] = e & 0x3FFFFF;
  }
  // scale this bucket's h1 rows: h1b = h1u * dis[row]  (2 bf16 per uint)
  const unsigned* hu = (const unsigned*)(h1u + (size_t)n0 * HD);
  unsigned* hb = (unsigned*)(h1b + (size_t)n0 * HD);
  int total = nn * (HD / 2);
  for (int i = t; i < total; i += 512) {
    int r = i >> 4;
    float d = disl[r];
    unsigned u = hu[i];
    hb[i] = (unsigned)f2b(b2f_lo(u) * d) | ((unsigned)f2b(b2f_hi(u) * d) << 16);
  }
}

// ---------------- wide-gather accumulate core ----------------
__device__ inline void gather8(const unsigned short* __restrict__ h, const int* __restrict__ csr,
                               int jb, int cnt, int es, int cg,
                               float& a0, float& a1, float& a2, float& a3,
                               float& a4, float& a5, float& a6, float& a7) {
  for (int j = 0; j < cnt; j += 8) {
    int eidx = j + es;
    int sidx = csr[jb + min(eidx, cnt - 1)];
    uint4 u = *(const uint4*)&h[(size_t)sidx * HD + cg * 8];
    if (eidx >= cnt) u = make_uint4(0, 0, 0, 0);
    a0 += b2f_lo(u.x); a1 += b2f_hi(u.x);
    a2 += b2f_lo(u.y); a3 += b2f_hi(u.y);
    a4 += b2f_lo(u.z); a5 += b2f_hi(u.z);
    a6 += b2f_lo(u.w); a7 += b2f_hi(u.w);
  }
#pragma unroll
  for (int o = 4; o <= 16; o <<= 1) {
    a0 += __shfl_xor(a0, o, 32); a1 += __shfl_xor(a1, o, 32);
    a2 += __shfl_xor(a2, o, 32); a3 += __shfl_xor(a3, o, 32);
    a4 += __shfl_xor(a4, o, 32); a5 += __shfl_xor(a5, o, 32);
    a6 += __shfl_xor(a6, o, 32); a7 += __shfl_xor(a7, o, 32);
  }
}

// ---------------- layer1 slim: pull + bias + relu -> t rows ----------------
__global__ __launch_bounds__(256) void k_pull1(const unsigned short* __restrict__ h1b,
                                               const int* __restrict__ csr, const int* __restrict__ offsets,
                                               const int* __restrict__ cntm1, const float* __restrict__ dis,
                                               const float* __restrict__ b1, unsigned short* __restrict__ tt,
                                               int N) {
  __shared__ float bb[HD];
  int t = threadIdx.x;
  if (t < HD) bb[t] = b1[t];
  __syncthreads();

  int lane = t & 63, L = lane & 31;
  int es = L >> 2, cg = L & 3;
  int halfId = (blockIdx.x * 4 + (t >> 6)) * 2 + (lane >> 5);
  int stride = gridDim.x * 8;
  for (int i = halfId; i < N; i += stride) {
    float a0 = 0.f, a1 = 0.f, a2 = 0.f, a3 = 0.f, a4 = 0.f, a5 = 0.f, a6 = 0.f, a7 = 0.f;
    gather8(h1b, csr, offsets[i], cntm1[i], es, cg, a0, a1, a2, a3, a4, a5, a6, a7);
    if (L < 4) {  // lanes 0-3 of each half hold full sums for cols cg*8..cg*8+7
      uint4 su = *(const uint4*)&h1b[(size_t)i * HD + cg * 8];
      float d = dis[i];
      const float* bp = &bb[cg * 8];
      float v0 = fmaxf(fmaf(d, a0 + b2f_lo(su.x), bp[0]), 0.f);
      float v1 = fmaxf(fmaf(d, a1 + b2f_hi(su.x), bp[1]), 0.f);
      float v2 = fmaxf(fmaf(d, a2 + b2f_lo(su.y), bp[2]), 0.f);
      float v3 = fmaxf(fmaf(d, a3 + b2f_hi(su.y), bp[3]), 0.f);
      float v4 = fmaxf(fmaf(d, a4 + b2f_lo(su.z), bp[4]), 0.f);
      float v5 = fmaxf(fmaf(d, a5 + b2f_hi(su.z), bp[5]), 0.f);
      float v6 = fmaxf(fmaf(d, a6 + b2f_lo(su.w), bp[6]), 0.f);
      float v7 = fmaxf(fmaf(d, a7 + b2f_hi(su.w), bp[7]), 0.f);
      uint4 pk;
      pk.x = (unsigned)f2b(v0) | ((unsigned)f2b(v1) << 16);
      pk.y = (unsigned)f2b(v2) | ((unsigned)f2b(v3) << 16);
      pk.z = (unsigned)f2b(v4) | ((unsigned)f2b(v5) << 16);
      pk.w = (unsigned)f2b(v6) | ((unsigned)f2b(v7) << 16);
      *(uint4*)&tt[(size_t)i * HD + cg * 8] = pk;
    }
  }
}

// ---------------- mm2 via MFMA: h2b = bf16((t @ W2) * dis[row]) ----------------
#define WP2 36
__global__ __launch_bounds__(512) void k_mm2(const unsigned short* __restrict__ tt,
                                             const float* __restrict__ W2, const float* __restrict__ dis,
                                             unsigned short* __restrict__ h2b, int N) {
  __shared__ unsigned short wT2[32 * WP2];
  const int t = threadIdx.x;
  const int rbase = blockIdx.x * 128;
  for (int idx = t; idx < HD * HD; idx += 512) {  // FIX: full 1024 entries with 512 threads
    int k = idx >> 5, c = idx & 31;
    wT2[c * WP2 + k] = f2b(W2[idx]);
  }
  __syncthreads();

  const int lane = t & 63;
  const int wrow = (t >> 6) * 16;
  const int m16 = lane & 15;
  const int kg = lane >> 4;

  int arow = rbase + wrow + m16;
  s16x8 a = {0, 0, 0, 0, 0, 0, 0, 0};
  if (arow < N) a = *(const s16x8*)&tt[(size_t)arow * HD + kg * 8];
  s16x8 b0 = *(const s16x8*)&wT2[m16 * WP2 + kg * 8];
  s16x8 b1 = *(const s16x8*)&wT2[(16 + m16) * WP2 + kg * 8];
  f32x4 z = {0.f, 0.f, 0.f, 0.f};
  f32x4 acc0 = __builtin_amdgcn_mfma_f32_16x16x32_bf16(a, b0, z, 0, 0, 0);
  f32x4 acc1 = __builtin_amdgcn_mfma_f32_16x16x32_bf16(a, b1, z, 0, 0, 0);

#pragma unroll
  for (int r = 0; r < 4; ++r) {
    int row = rbase + wrow + kg * 4 + r;
    if (row < N) {
      float dr = dis[row];
      h2b[(size_t)row * HD + m16]      = f2b(acc0[r] * dr);
      h2b[(size_t)row * HD + 16 + m16] = f2b(acc1[r] * dr);
    }
  }
}

// ---------------- layer2: wide pull + bias + log_softmax -> out ----------------
__global__ __launch_bounds__(256) void k_pull2_lsm(const unsigned short* __restrict__ h2b,
                                                   const int* __restrict__ csr, const int* __restrict__ offsets,
                                                   const int* __restrict__ cntm1, const float* __restrict__ dis,
                                                   const float* __restrict__ b2, float* __restrict__ out, int N) {
  __shared__ float bb[HD];
  int t = threadIdx.x;
  if (t < HD) bb[t] = b2[t];
  __syncthreads();

  int lane = t & 63, L = lane & 31;
  int es = L >> 2, cg = L & 3;
  int halfId = (blockIdx.x * 4 + (t >> 6)) * 2 + (lane >> 5);
  int stride = gridDim.x * 8;
  for (int i = halfId; i < N; i += stride) {
    float a0 = 0.f, a1 = 0.f, a2 = 0.f, a3 = 0.f, a4 = 0.f, a5 = 0.f, a6 = 0.f, a7 = 0.f;
    gather8(h2b, csr, offsets[i], cntm1[i], es, cg, a0, a1, a2, a3, a4, a5, a6, a7);
    int srcl = L >> 3;
    int sel = L & 7;
    float sum = __shfl(a0, srcl, 32);
    float c;
    c = __shfl(a1, srcl, 32); sum = (sel == 1) ? c : sum;
    c = __shfl(a2, srcl, 32); sum = (sel == 2) ? c : sum;
    c = __shfl(a3, srcl, 32); sum = (sel == 3) ? c : sum;
    c = __shfl(a4, srcl, 32); sum = (sel == 4) ? c : sum;
    c = __shfl(a5, srcl, 32); sum = (sel == 5) ? c : sum;
    c = __shfl(a6, srcl, 32); sum = (sel == 6) ? c : sum;
    c = __shfl(a7, srcl, 32); sum = (sel == 7) ? c : sum;

    sum += b2f(h2b[(size_t)i * HD + L]);  // self
    float v = fmaf(dis[i], sum, bb[L]);
    float m = v;
    for (int off = 16; off; off >>= 1) m = fmaxf(m, __shfl_xor(m, off, 32));
    float ex = __expf(v - m);
    float sm = ex;
    for (int off = 16; off; off >>= 1) sm += __shfl_xor(sm, off, 32);
    out[(size_t)i * HD + L] = v - m - __logf(sm);
  }
}

extern "C" void kernel_launch(void* const* d_in, const int* in_sizes, int n_in,
                              void* d_out, int out_size, void* d_ws, size_t ws_size,
                              hipStream_t stream) {
  const float* x  = (const float*)d_in[0];
  const int*   ei = (const int*)d_in[1];
  const float* W1 = (const float*)d_in[2];
  const float* b1 = (const float*)d_in[3];
  const float* W2 = (const float*)d_in[4];
  const float* b2 = (const float*)d_in[5];
  float* out = (float*)d_out;

  const int H   = in_sizes[3];            // 32
  const int Fin = in_sizes[2] / H;        // 512
  const int N   = in_sizes[0] / Fin;      // 100000
  const int E   = in_sizes[1] / 2;        // 3200000
  const int* src = ei;
  const int* dst = ei + E;
  const int B    = (N + BNODES - 1) / BNODES;  // 196 buckets
  const int NBIN = (E + CH - 1) / CH;          // 391 bin blocks
  const int NMM1 = (N + 127) / 128;            // 782 mm1 blocks

  char* wsp = (char*)d_ws;
  size_t off = 0;
  auto nxt = [&](size_t bytes) { char* p = wsp + off; off = (off + bytes + 255) & ~(size_t)255; return p; };
  int*   hist    = (int*)  nxt((size_t)NHB * 256 * 4);
  int*   bcnt    = (int*)  nxt(256 * 4);
  int*   bbase   = (int*)  nxt(256 * 4);
  int*   bfill   = (int*)  nxt(256 * 4);
  int*   cntm1   = (int*)  nxt((size_t)N * 4);
  float* dis     = (float*)nxt((size_t)N * 4);
  int*   offsets = (int*)  nxt((size_t)N * 4);
  int*   bin     = (int*)  nxt((size_t)E * 4);
  int*   csr     = (int*)  nxt((size_t)E * 4);
  unsigned short* h1u = (unsigned short*)nxt((size_t)N * HD * 2);
  unsigned short* h1b = (unsigned short*)nxt((size_t)N * HD * 2);
  unsigned short* tt  = (unsigned short*)nxt((size_t)N * HD * 2);
  unsigned short* h2b = (unsigned short*)nxt((size_t)N * HD * 2);
  (void)ws_size; (void)n_in; (void)out_size;

  k_bktcnt<<<NHB, 256, 0, stream>>>(dst, hist, E);
  k_bscan<<<1, 256, 0, stream>>>(hist, bcnt, bbase, bfill);
  k_fused<<<NBIN + NMM1, 512, 0, stream>>>(src, dst, bfill, bin, E, NBIN, x, W1, h1u, N);
  k_csr<<<B, 512, 0, stream>>>(bin, bbase, bcnt, cntm1, dis, offsets, csr, h1u, h1b, N);
  k_pull1<<<2048, 256, 0, stream>>>(h1b, csr, offsets, cntm1, dis, b1, tt, N);
  k_mm2<<<NMM1, 512, 0, stream>>>(tt, W2, dis, h2b, N);
  k_pull2_lsm<<<2048, 256, 0, stream>>>(h2b, csr, offsets, cntm1, dis, b2, out, N);
}

// Round 15
// 218.771 us; speedup vs baseline: 6.8492x; 1.0522x over previous
//
#include <hip/hip_runtime.h>
#include <hip/hip_bf16.h>

#define FIN 512
#define HD 32
#define BNODES 512   // nodes per dst-bucket (bucket = dst >> 9)
#define CH 8192      // edges per bin chunk
#define NHB 128      // partial-histogram blocks

typedef short s16x8 __attribute__((ext_vector_type(8)));
typedef float f32x4 __attribute__((ext_vector_type(4)));

__device__ inline unsigned short f2b(float f) {  // fp32 -> bf16 bits, RNE
  unsigned u = __float_as_uint(f);
  return (unsigned short)((u + 0x7FFFu + ((u >> 16) & 1u)) >> 16);
}
__device__ inline float b2f(unsigned short b) {
  return __uint_as_float((unsigned)b << 16);
}
__device__ inline float b2f_lo(unsigned u) { return __uint_as_float(u << 16); }
__device__ inline float b2f_hi(unsigned u) { return __uint_as_float(u & 0xFFFF0000u); }

// ---------------- per-block partial histograms over dst>>9 ----------------
__global__ __launch_bounds__(256) void k_bktcnt(const int* __restrict__ dst, int* __restrict__ hist, int E) {
  __shared__ int h[256];
  int t = threadIdx.x;
  h[t] = 0;
  __syncthreads();
  for (int i = blockIdx.x * 256 + t; i < E; i += gridDim.x * 256)
    atomicAdd(&h[dst[i] >> 9], 1);
  __syncthreads();
  hist[blockIdx.x * 256 + t] = h[t];
}

__global__ __launch_bounds__(256) void k_bscan(const int* __restrict__ hist, int* __restrict__ bcnt,
                                               int* __restrict__ bbase, int* __restrict__ bfill) {
  __shared__ int s[256];
  int t = threadIdx.x;
  int v = 0;
  for (int b = 0; b < NHB; ++b) v += hist[b * 256 + t];
  bcnt[t] = v;
  s[t] = v;
  __syncthreads();
  for (int o = 1; o < 256; o <<= 1) {
    int a = (t >= o) ? s[t - o] : 0;
    __syncthreads();
    s[t] += a;
    __syncthreads();
  }
  bbase[t] = s[t] - v;
  bfill[t] = s[t] - v;
}

// ---------------- fused: [coarse bin] || [mm1 unscaled] ----------------
#define XPAD 72
#define WPAD 520
#define SMEM_BYTES 51712
__global__ __launch_bounds__(512) void k_fused(const int* __restrict__ src, const int* __restrict__ dst,
                                               int* __restrict__ bfill, int* __restrict__ bin, int E, int NBIN,
                                               const float* __restrict__ x, const float* __restrict__ W1,
                                               unsigned short* __restrict__ h1u, int N) {
  __shared__ __align__(16) char smem[SMEM_BYTES];
  const int t = threadIdx.x;

  if (blockIdx.x < NBIN) {
    int* raw = (int*)smem;                                   // 32768 B
    unsigned short* bkt = (unsigned short*)(smem + 32768);   // 16384 B
    int* cnt = (int*)(smem + 49152);                         // 1024 B
    int* gbase = (int*)(smem + 50176);                       // 1024 B
    int cb = blockIdx.x * CH;
    int n = E - cb; if (n > CH) n = CH;
    if (t < 256) cnt[t] = 0;
    __syncthreads();
    for (int j = t; j < n; j += 512) {
      int s = src[cb + j], d = dst[cb + j];
      raw[j] = s | ((d & 511) << 22);
      bkt[j] = (unsigned short)(d >> 9);
      atomicAdd(&cnt[d >> 9], 1);
    }
    __syncthreads();
    if (t < 256) {
      int c = cnt[t];
      gbase[t] = (c > 0) ? atomicAdd(&bfill[t], c) : 0;
      cnt[t] = 0;
    }
    __syncthreads();
    for (int j = t; j < n; j += 512) {
      int b = bkt[j];
      int r = atomicAdd(&cnt[b], 1);
      bin[gbase[b] + r] = raw[j];
    }
  } else {
    unsigned short* wT = (unsigned short*)smem;              // 33280 B
    unsigned short* xs = (unsigned short*)(smem + 33280);    // 18432 B
    const int rbase = (blockIdx.x - NBIN) * 128;

    for (int idx = t; idx < FIN * HD; idx += 512) {
      int k = idx >> 5, c = idx & 31;
      wT[c * WPAD + k] = f2b(W1[idx]);
    }

    const int lane = t & 63;
    const int wrow = (t >> 6) * 16;
    const int m16 = lane & 15;
    const int kg = lane >> 4;

    f32x4 acc0 = {0.f, 0.f, 0.f, 0.f};
    f32x4 acc1 = {0.f, 0.f, 0.f, 0.f};

    for (int kc = 0; kc < FIN; kc += 64) {
      __syncthreads();
#pragma unroll
      for (int p = 0; p < 4; ++p) {
        int idx = p * 512 + t;
        int r = idx >> 4, kq = idx & 15;
        int grow = rbase + r;
        float4 v = (grow < N) ? *(const float4*)&x[(size_t)grow * FIN + kc + kq * 4]
                              : make_float4(0.f, 0.f, 0.f, 0.f);
        unsigned p0 = (unsigned)f2b(v.x) | ((unsigned)f2b(v.y) << 16);
        unsigned p1 = (unsigned)f2b(v.z) | ((unsigned)f2b(v.w) << 16);
        *(uint2*)&xs[r * XPAD + kq * 4] = make_uint2(p0, p1);
      }
      __syncthreads();

      s16x8 a0  = *(const s16x8*)&xs[(wrow + m16) * XPAD + kg * 8];
      s16x8 a1  = *(const s16x8*)&xs[(wrow + m16) * XPAD + 32 + kg * 8];
      s16x8 b00 = *(const s16x8*)&wT[m16 * WPAD + kc + kg * 8];
      s16x8 b01 = *(const s16x8*)&wT[(16 + m16) * WPAD + kc + kg * 8];
      s16x8 b10 = *(const s16x8*)&wT[m16 * WPAD + kc + 32 + kg * 8];
      s16x8 b11 = *(const s16x8*)&wT[(16 + m16) * WPAD + kc + 32 + kg * 8];
      acc0 = __builtin_amdgcn_mfma_f32_16x16x32_bf16(a0, b00, acc0, 0, 0, 0);
      acc1 = __builtin_amdgcn_mfma_f32_16x16x32_bf16(a0, b01, acc1, 0, 0, 0);
      acc0 = __builtin_amdgcn_mfma_f32_16x16x32_bf16(a1, b10, acc0, 0, 0, 0);
      acc1 = __builtin_amdgcn_mfma_f32_16x16x32_bf16(a1, b11, acc1, 0, 0, 0);
    }

#pragma unroll
    for (int r = 0; r < 4; ++r) {
      int row = rbase + wrow + kg * 4 + r;
      if (row < N) {
        h1u[(size_t)row * HD + m16]      = f2b(acc0[r]);
        h1u[(size_t)row * HD + 16 + m16] = f2b(acc1[r]);
      }
    }
  }
}

// ---------------- per-bucket exact CSR + deg/dis/offsets + h1 scale ----------------
__global__ __launch_bounds__(512) void k_csr(const int* __restrict__ bin, const int* __restrict__ bbase,
                                             const int* __restrict__ bcnt, int* __restrict__ cntm1,
                                             float* __restrict__ dis, int* __restrict__ offsets,
                                             int* __restrict__ csr, const unsigned short* __restrict__ h1u,
                                             unsigned short* __restrict__ h1b, int N) {
  __shared__ int cnt[BNODES];
  __shared__ int sc[BNODES];
  __shared__ float disl[BNODES];
  const int t = threadIdx.x;
  const int bkt = blockIdx.x;
  const int n0 = bkt * BNODES;
  int nn = N - n0; if (nn > BNODES) nn = BNODES;
  const int eb = bbase[bkt], ec = bcnt[bkt];

  cnt[t] = 0;
  __syncthreads();
  for (int j = t; j < ec; j += 512)
    atomicAdd(&cnt[(unsigned)bin[eb + j] >> 22], 1);
  __syncthreads();
  int v = cnt[t];
  float dv = rsqrtf((float)(v + 1));
  if (t < nn) {
    cntm1[n0 + t] = v;
    dis[n0 + t] = dv;
    disl[t] = dv;
  }
  sc[t] = v;
  __syncthreads();
  for (int o = 1; o < 512; o <<= 1) {
    int a = (t >= o) ? sc[t - o] : 0;
    __syncthreads();
    sc[t] += a;
    __syncthreads();
  }
  int myoff = sc[t] - v;
  if (t < nn) offsets[n0 + t] = eb + myoff;
  cnt[t] = myoff;
  __syncthreads();
  for (int j = t; j < ec; j += 512) {
    int e = bin[eb + j];
    int pos = atomicAdd(&cnt[(unsigned)e >> 22], 1);
    csr[eb + pos] = e & 0x3FFFFF;
  }
  // scale this bucket's h1 rows: h1b = h1u * dis[row]
  const unsigned* hu = (const unsigned*)(h1u + (size_t)n0 * HD);
  unsigned* hb = (unsigned*)(h1b + (size_t)n0 * HD);
  int total = nn * (HD / 2);
  for (int i = t; i < total; i += 512) {
    int r = i >> 4;
    float d = disl[r];
    unsigned u = hu[i];
    hb[i] = (unsigned)f2b(b2f_lo(u) * d) | ((unsigned)f2b(b2f_hi(u) * d) << 16);
  }
}

// ---------------- wide-gather accumulate core, 2-deep iteration interleave ----------------
// Edges j..j+7 and j+8..j+15 issued as independent idx+gather pairs:
// ~8 loads in flight per wave (vs 4), zero extra shuffle/epilogue cost.
__device__ inline void gather8(const unsigned short* __restrict__ h, const int* __restrict__ csr,
                               int jb, int cnt, int es, int cg,
                               float& a0, float& a1, float& a2, float& a3,
                               float& a4, float& a5, float& a6, float& a7) {
  int j = 0;
  for (; j + 16 <= cnt; j += 16) {  // two full groups, no masking
    int s0 = csr[jb + j + es];
    int s1 = csr[jb + j + 8 + es];
    uint4 u = *(const uint4*)&h[(size_t)s0 * HD + cg * 8];
    uint4 w = *(const uint4*)&h[(size_t)s1 * HD + cg * 8];
    a0 += b2f_lo(u.x); a1 += b2f_hi(u.x);
    a2 += b2f_lo(u.y); a3 += b2f_hi(u.y);
    a4 += b2f_lo(u.z); a5 += b2f_hi(u.z);
    a6 += b2f_lo(u.w); a7 += b2f_hi(u.w);
    a0 += b2f_lo(w.x); a1 += b2f_hi(w.x);
    a2 += b2f_lo(w.y); a3 += b2f_hi(w.y);
    a4 += b2f_lo(w.z); a5 += b2f_hi(w.z);
    a6 += b2f_lo(w.w); a7 += b2f_hi(w.w);
  }
  for (; j < cnt; j += 8) {  // masked tail group(s)
    int eidx = j + es;
    int sidx = csr[jb + min(eidx, cnt - 1)];
    uint4 u = *(const uint4*)&h[(size_t)sidx * HD + cg * 8];
    if (eidx >= cnt) u = make_uint4(0, 0, 0, 0);
    a0 += b2f_lo(u.x); a1 += b2f_hi(u.x);
    a2 += b2f_lo(u.y); a3 += b2f_hi(u.y);
    a4 += b2f_lo(u.z); a5 += b2f_hi(u.z);
    a6 += b2f_lo(u.w); a7 += b2f_hi(u.w);
  }
#pragma unroll
  for (int o = 4; o <= 16; o <<= 1) {
    a0 += __shfl_xor(a0, o, 32); a1 += __shfl_xor(a1, o, 32);
    a2 += __shfl_xor(a2, o, 32); a3 += __shfl_xor(a3, o, 32);
    a4 += __shfl_xor(a4, o, 32); a5 += __shfl_xor(a5, o, 32);
    a6 += __shfl_xor(a6, o, 32); a7 += __shfl_xor(a7, o, 32);
  }
}

// ---------------- layer1 slim: pull + bias + relu -> t rows ----------------
__global__ __launch_bounds__(256) void k_pull1(const unsigned short* __restrict__ h1b,
                                               const int* __restrict__ csr, const int* __restrict__ offsets,
                                               const int* __restrict__ cntm1, const float* __restrict__ dis,
                                               const float* __restrict__ b1, unsigned short* __restrict__ tt,
                                               int N) {
  __shared__ float bb[HD];
  int t = threadIdx.x;
  if (t < HD) bb[t] = b1[t];
  __syncthreads();

  int lane = t & 63, L = lane & 31;
  int es = L >> 2, cg = L & 3;
  int halfId = (blockIdx.x * 4 + (t >> 6)) * 2 + (lane >> 5);
  int stride = gridDim.x * 8;
  for (int i = halfId; i < N; i += stride) {
    float a0 = 0.f, a1 = 0.f, a2 = 0.f, a3 = 0.f, a4 = 0.f, a5 = 0.f, a6 = 0.f, a7 = 0.f;
    gather8(h1b, csr, offsets[i], cntm1[i], es, cg, a0, a1, a2, a3, a4, a5, a6, a7);
    if (L < 4) {  // lanes 0-3 of each half hold full sums for cols cg*8..cg*8+7
      uint4 su = *(const uint4*)&h1b[(size_t)i * HD + cg * 8];
      float d = dis[i];
      const float* bp = &bb[cg * 8];
      float v0 = fmaxf(fmaf(d, a0 + b2f_lo(su.x), bp[0]), 0.f);
      float v1 = fmaxf(fmaf(d, a1 + b2f_hi(su.x), bp[1]), 0.f);
      float v2 = fmaxf(fmaf(d, a2 + b2f_lo(su.y), bp[2]), 0.f);
      float v3 = fmaxf(fmaf(d, a3 + b2f_hi(su.y), bp[3]), 0.f);
      float v4 = fmaxf(fmaf(d, a4 + b2f_lo(su.z), bp[4]), 0.f);
      float v5 = fmaxf(fmaf(d, a5 + b2f_hi(su.z), bp[5]), 0.f);
      float v6 = fmaxf(fmaf(d, a6 + b2f_lo(su.w), bp[6]), 0.f);
      float v7 = fmaxf(fmaf(d, a7 + b2f_hi(su.w), bp[7]), 0.f);
      uint4 pk;
      pk.x = (unsigned)f2b(v0) | ((unsigned)f2b(v1) << 16);
      pk.y = (unsigned)f2b(v2) | ((unsigned)f2b(v3) << 16);
      pk.z = (unsigned)f2b(v4) | ((unsigned)f2b(v5) << 16);
      pk.w = (unsigned)f2b(v6) | ((unsigned)f2b(v7) << 16);
      *(uint4*)&tt[(size_t)i * HD + cg * 8] = pk;
    }
  }
}

// ---------------- mm2 via MFMA: h2b = bf16((t @ W2) * dis[row]) ----------------
#define WP2 36
__global__ __launch_bounds__(512) void k_mm2(const unsigned short* __restrict__ tt,
                                             const float* __restrict__ W2, const float* __restrict__ dis,
                                             unsigned short* __restrict__ h2b, int N) {
  __shared__ unsigned short wT2[32 * WP2];
  const int t = threadIdx.x;
  const int rbase = blockIdx.x * 128;
  for (int idx = t; idx < HD * HD; idx += 512) {
    int k = idx >> 5, c = idx & 31;
    wT2[c * WP2 + k] = f2b(W2[idx]);
  }
  __syncthreads();

  const int lane = t & 63;
  const int wrow = (t >> 6) * 16;
  const int m16 = lane & 15;
  const int kg = lane >> 4;

  int arow = rbase + wrow + m16;
  s16x8 a = {0, 0, 0, 0, 0, 0, 0, 0};
  if (arow < N) a = *(const s16x8*)&tt[(size_t)arow * HD + kg * 8];
  s16x8 b0 = *(const s16x8*)&wT2[m16 * WP2 + kg * 8];
  s16x8 b1 = *(const s16x8*)&wT2[(16 + m16) * WP2 + kg * 8];
  f32x4 z = {0.f, 0.f, 0.f, 0.f};
  f32x4 acc0 = __builtin_amdgcn_mfma_f32_16x16x32_bf16(a, b0, z, 0, 0, 0);
  f32x4 acc1 = __builtin_amdgcn_mfma_f32_16x16x32_bf16(a, b1, z, 0, 0, 0);

#pragma unroll
  for (int r = 0; r < 4; ++r) {
    int row = rbase + wrow + kg * 4 + r;
    if (row < N) {
      float dr = dis[row];
      h2b[(size_t)row * HD + m16]      = f2b(acc0[r] * dr);
      h2b[(size_t)row * HD + 16 + m16] = f2b(acc1[r] * dr);
    }
  }
}

// ---------------- layer2: wide pull + bias + log_softmax -> out ----------------
__global__ __launch_bounds__(256) void k_pull2_lsm(const unsigned short* __restrict__ h2b,
                                                   const int* __restrict__ csr, const int* __restrict__ offsets,
                                                   const int* __restrict__ cntm1, const float* __restrict__ dis,
                                                   const float* __restrict__ b2, float* __restrict__ out, int N) {
  __shared__ float bb[HD];
  int t = threadIdx.x;
  if (t < HD) bb[t] = b2[t];
  __syncthreads();

  int lane = t & 63, L = lane & 31;
  int es = L >> 2, cg = L & 3;
  int halfId = (blockIdx.x * 4 + (t >> 6)) * 2 + (lane >> 5);
  int stride = gridDim.x * 8;
  for (int i = halfId; i < N; i += stride) {
    float a0 = 0.f, a1 = 0.f, a2 = 0.f, a3 = 0.f, a4 = 0.f, a5 = 0.f, a6 = 0.f, a7 = 0.f;
    gather8(h2b, csr, offsets[i], cntm1[i], es, cg, a0, a1, a2, a3, a4, a5, a6, a7);
    int srcl = L >> 3;
    int sel = L & 7;
    float sum = __shfl(a0, srcl, 32);
    float c;
    c = __shfl(a1, srcl, 32); sum = (sel == 1) ? c : sum;
    c = __shfl(a2, srcl, 32); sum = (sel == 2) ? c : sum;
    c = __shfl(a3, srcl, 32); sum = (sel == 3) ? c : sum;
    c = __shfl(a4, srcl, 32); sum = (sel == 4) ? c : sum;
    c = __shfl(a5, srcl, 32); sum = (sel == 5) ? c : sum;
    c = __shfl(a6, srcl, 32); sum = (sel == 6) ? c : sum;
    c = __shfl(a7, srcl, 32); sum = (sel == 7) ? c : sum;

    sum += b2f(h2b[(size_t)i * HD + L]);  // self
    float v = fmaf(dis[i], sum, bb[L]);
    float m = v;
    for (int off = 16; off; off >>= 1) m = fmaxf(m, __shfl_xor(m, off, 32));
    float ex = __expf(v - m);
    float sm = ex;
    for (int off = 16; off; off >>= 1) sm += __shfl_xor(sm, off, 32);
    out[(size_t)i * HD + L] = v - m - __logf(sm);
  }
}

extern "C" void kernel_launch(void* const* d_in, const int* in_sizes, int n_in,
                              void* d_out, int out_size, void* d_ws, size_t ws_size,
                              hipStream_t stream) {
  const float* x  = (const float*)d_in[0];
  const int*   ei = (const int*)d_in[1];
  const float* W1 = (const float*)d_in[2];
  const float* b1 = (const float*)d_in[3];
  const float* W2 = (const float*)d_in[4];
  const float* b2 = (const float*)d_in[5];
  float* out = (float*)d_out;

  const int H   = in_sizes[3];            // 32
  const int Fin = in_sizes[2] / H;        // 512
  const int N   = in_sizes[0] / Fin;      // 100000
  const int E   = in_sizes[1] / 2;        // 3200000
  const int* src = ei;
  const int* dst = ei + E;
  const int B    = (N + BNODES - 1) / BNODES;  // 196 buckets
  const int NBIN = (E + CH - 1) / CH;          // 391 bin blocks
  const int NMM1 = (N + 127) / 128;            // 782 mm1 blocks

  char* wsp = (char*)d_ws;
  size_t off = 0;
  auto nxt = [&](size_t bytes) { char* p = wsp + off; off = (off + bytes + 255) & ~(size_t)255; return p; };
  int*   hist    = (int*)  nxt((size_t)NHB * 256 * 4);
  int*   bcnt    = (int*)  nxt(256 * 4);
  int*   bbase   = (int*)  nxt(256 * 4);
  int*   bfill   = (int*)  nxt(256 * 4);
  int*   cntm1   = (int*)  nxt((size_t)N * 4);
  float* dis     = (float*)nxt((size_t)N * 4);
  int*   offsets = (int*)  nxt((size_t)N * 4);
  int*   bin     = (int*)  nxt((size_t)E * 4);
  int*   csr     = (int*)  nxt((size_t)E * 4);
  unsigned short* h1u = (unsigned short*)nxt((size_t)N * HD * 2);
  unsigned short* h1b = (unsigned short*)nxt((size_t)N * HD * 2);
  unsigned short* tt  = (unsigned short*)nxt((size_t)N * HD * 2);
  unsigned short* h2b = (unsigned short*)nxt((size_t)N * HD * 2);
  (void)ws_size; (void)n_in; (void)out_size;

  k_bktcnt<<<NHB, 256, 0, stream>>>(dst, hist, E);
  k_bscan<<<1, 256, 0, stream>>>(hist, bcnt, bbase, bfill);
  k_fused<<<NBIN + NMM1, 512, 0, stream>>>(src, dst, bfill, bin, E, NBIN, x, W1, h1u, N);
  k_csr<<<B, 512, 0, stream>>>(bin, bbase, bcnt, cntm1, dis, offsets, csr, h1u, h1b, N);
  k_pull1<<<2048, 256, 0, stream>>>(h1b, csr, offsets, cntm1, dis, b1, tt, N);
  k_mm2<<<NMM1, 512, 0, stream>>>(tt, W2, dis, h2b, N);
  k_pull2_lsm<<<2048, 256, 0, stream>>>(h2b, csr, offsets, cntm1, dis, b2, out, N);
}